// Round 16
// baseline (563.472 us; speedup 1.0000x reference)
//
#include <hip/hip_runtime.h>

typedef __bf16 bf16_t;
typedef __bf16 bf16x4 __attribute__((ext_vector_type(4)));
typedef __bf16 bf16x8 __attribute__((ext_vector_type(8)));
typedef float  f32x4  __attribute__((ext_vector_type(4)));
typedef float  f32x16 __attribute__((ext_vector_type(16)));
typedef unsigned int u32;

#define MFMA16(a, b, c) __builtin_amdgcn_mfma_f32_16x16x32_bf16((a), (b), (c), 0, 0, 0)
#define MFMA32(a, b, c) __builtin_amdgcn_mfma_f32_32x32x16_bf16((a), (b), (c), 0, 0, 0)

__device__ __forceinline__ void gld_lds16(const bf16_t* g, bf16_t* l) {
  __builtin_amdgcn_global_load_lds((__attribute__((address_space(1))) void*)g,
                                   (__attribute__((address_space(3))) void*)l, 16, 0, 0);
}
__device__ __forceinline__ u32 cvt_pk_bf16(float lo, float hi) {
  u32 r;
  asm("v_cvt_pk_bf16_f32 %0, %1, %2" : "=v"(r) : "v"(lo), "v"(hi));
  return r;
}

// ---------------- prep: x cast (big) ----------------
__global__ void cast_f32_bf16(const float* __restrict__ s, bf16_t* __restrict__ d, int n) {
  int i = (blockIdx.x * blockDim.x + threadIdx.x) * 4;
  if (i >= n) return;
  float4 v = *(const float4*)(s + i);
  bf16x4 o;
  o[0] = (bf16_t)v.x; o[1] = (bf16_t)v.y; o[2] = (bf16_t)v.z; o[3] = (bf16_t)v.w;
  *(bf16x4*)(d + i) = o;
}

// ---------------- prep: all weight casts + bias concat in one launch ----------------
__global__ void prep_w(const float* __restrict__ Wq, const float* __restrict__ Wk,
                       const float* __restrict__ Wv, const float* __restrict__ Wo,
                       const float* __restrict__ bq, const float* __restrict__ bk,
                       const float* __restrict__ bv,
                       bf16_t* __restrict__ wqkv, bf16_t* __restrict__ wob,
                       float* __restrict__ qkvb) {
  const int NW = 768 * 768;
  const int t = blockIdx.x * 256 + threadIdx.x;
  const int i = t * 4;
  if (i < 3 * NW) {
    const float* s; int off;
    if (i < NW)          { s = Wq; off = i; }
    else if (i < 2 * NW) { s = Wk; off = i - NW; }
    else                 { s = Wv; off = i - 2 * NW; }
    float4 v = *(const float4*)(s + off);
    bf16x4 o;
    o[0] = (bf16_t)v.x; o[1] = (bf16_t)v.y; o[2] = (bf16_t)v.z; o[3] = (bf16_t)v.w;
    *(bf16x4*)(wqkv + i) = o;
  } else if (i < 4 * NW) {
    const int off = i - 3 * NW;
    float4 v = *(const float4*)(Wo + off);
    bf16x4 o;
    o[0] = (bf16_t)v.x; o[1] = (bf16_t)v.y; o[2] = (bf16_t)v.z; o[3] = (bf16_t)v.w;
    *(bf16x4*)(wob + off) = o;
  }
  if (t < 2304) qkvb[t] = t < 768 ? bq[t] : (t < 1536 ? bk[t - 768] : bv[t - 1536]);
}

// ---------------- fused QKV GEMM (R9-verified body) + XCD bm-affinity + occupancy bound ----------------
// __launch_bounds__(256,5): 5 waves/EU -> 5 blocks/CU; caps VGPR at ~102 (body fits in 92).
// R15 profile showed VGPR=136 (3 blocks/CU) — occupancy, not L3, was the regression.
__global__ __launch_bounds__(256, 5) void gemm_qkv(
    const bf16_t* __restrict__ A, const bf16_t* __restrict__ B,
    const float* __restrict__ bias,
    bf16_t* __restrict__ qb, bf16_t* __restrict__ kb2, bf16_t* __restrict__ vtb) {
  __shared__ __align__(16) bf16_t As[128 * 64];
  __shared__ __align__(16) bf16_t Bs[128 * 64];
  const int K = 768;
  const int p = blockIdx.x;
  const int xcd = p & 7, u = p >> 3;           // u in 0..143
  const int bm = xcd * 8 + u / 18;             // 8 bm rows per XCD
  const int bn = u - (u / 18) * 18;            // bn fastest within a bm
  const int tid = threadIdx.x;
  const int w = tid >> 6, l = tid & 63, lg = l >> 4, ln = l & 15;
  const int wr = w >> 1, wc = w & 1;
  const int lr8 = l >> 3, lc8 = l & 7;
  const int region = (bn * 128) / 768;
  const int ln7 = ln & 7;
  f32x4 acc[4][4] = {};
  for (int kb = 0; kb < K / 64; ++kb) {
    const int k0 = kb * 64;
#pragma unroll
    for (int i = 0; i < 4; ++i) {
      const int row = w * 32 + i * 8 + lr8;
      const int so = k0 + ((lc8 ^ (row & 7)) << 3);     // pre-swizzled source col
      gld_lds16(A + (size_t)(bm * 128 + row) * K + so, As + (w * 32 + i * 8) * 64 + l * 8);
      gld_lds16(B + (size_t)(bn * 128 + row) * K + so, Bs + (w * 32 + i * 8) * 64 + l * 8);
    }
    __syncthreads();
#pragma unroll
    for (int kk = 0; kk < 2; ++kk) {
      bf16x8 af[4], bfr[4];
#pragma unroll
      for (int m = 0; m < 4; ++m) {
        const int jc = ((kk * 4 + lg) ^ ln7) << 3;      // swizzled chunk read
        af[m]  = *(const bf16x8*)(As + (wr * 64 + m * 16 + ln) * 64 + jc);
        bfr[m] = *(const bf16x8*)(Bs + (wc * 64 + m * 16 + ln) * 64 + jc);
      }
      if (region != 2) {
#pragma unroll
        for (int m = 0; m < 4; ++m)
#pragma unroll
          for (int n = 0; n < 4; ++n) acc[m][n] = MFMA16(af[m], bfr[n], acc[m][n]);
      } else {  // C^T for coalesced [B,H,D,T] writes
#pragma unroll
        for (int m = 0; m < 4; ++m)
#pragma unroll
          for (int n = 0; n < 4; ++n) acc[m][n] = MFMA16(bfr[n], af[m], acc[m][n]);
      }
    }
    __syncthreads();
  }
  if (region != 2) {
    const float scl = (region == 0) ? 0.18033688011112042f : 1.0f;  // 0.125*log2(e)
    bf16_t* dst = region == 0 ? qb : kb2;
#pragma unroll
    for (int m = 0; m < 4; ++m)
#pragma unroll
      for (int n = 0; n < 4; ++n)
#pragma unroll
        for (int j = 0; j < 4; ++j) {
          const int gm = bm * 128 + wr * 64 + m * 16 + lg * 4 + j;   // t
          const int gn = bn * 128 + wc * 64 + n * 16 + ln;           // qkv col
          const float v = (acc[m][n][j] + bias[gn]) * scl;
          const int c = gn - region * 768;
          const int bb = gm >> 12, tt = gm & 4095;
          const int hh = c >> 6, d = c & 63;
          dst[((size_t)(bb * 12 + hh) * 4096 + tt) * 64 + d] = (bf16_t)v;
        }
  } else {  // transposed acc: C-row = channel, C-col = t (lanes ln -> consecutive t)
#pragma unroll
    for (int m = 0; m < 4; ++m)
#pragma unroll
      for (int n = 0; n < 4; ++n)
#pragma unroll
        for (int j = 0; j < 4; ++j) {
          const int gn = bn * 128 + wc * 64 + n * 16 + lg * 4 + j;   // qkv col (channel)
          const int gm = bm * 128 + wr * 64 + m * 16 + ln;           // t
          const float v = acc[m][n][j] + bias[gn];
          const int c = gn - 1536;
          const int bb = gm >> 12, tt = gm & 4095;
          const int hh = c >> 6, d = c & 63;
          vtb[((size_t)(bb * 12 + hh) * 64 + d) * 4096 + tt] = (bf16_t)v;
        }
  }
}

// ---------------- flash attention (R15-verified): shared-tile k-split, 32KB LDS ----------------
__global__ __launch_bounds__(512) void attn_fwd(
    const bf16_t* __restrict__ q, const bf16_t* __restrict__ k,
    const bf16_t* __restrict__ vt, bf16_t* __restrict__ y) {
  __shared__ __align__(16) unsigned char SMEM[33280];
  bf16_t* Ks = (bf16_t*)SMEM;            // [dbuf][4096] (8KB per buf)
  bf16_t* Vs = (bf16_t*)(SMEM + 16384);  // [dbuf][4096]
  float*  osh = (float*)SMEM;            // combine: [4][32][64] f32 (32KB)
  float*  lsh = (float*)(SMEM + 32768);  // combine: [4][32] f32 row sums

  const int p = blockIdx.x;
  const int xcd = p & 7, slot = p >> 3;        // 96 slots per XCD
  const int hb = xcd + 8 * (slot % 3);         // 3 heads per XCD (L2-resident K/V)
  const int qt = 31 - slot / 3;                // heavy-first
  const int tid = threadIdx.x;
  const int w = tid >> 6, l = tid & 63, lq = l & 31, lh = l >> 5;
  const int wq = w >> 1, wc = w & 1;
  const size_t hbo = (size_t)hb * (4096 * 64);
  const bf16_t* qh = q + hbo;
  const bf16_t* kh = k + hbo;
  const bf16_t* vh = vt + hbo;

  const int q0 = qt * 128 + wq * 32;           // wave's first q row
  const int qidx = q0 + lq;                    // this lane's q row
  const int nst = 2 * qt + 2;                  // tiles to sweep (each once)

  const int sr = ((tid >> 8) << 5) | (tid & 31);
  const int sc = ((((tid >> 6) & 3) << 1) | ((tid >> 5) & 1)) << 3;
  const bf16_t* ksrc = kh + ((size_t)sr * 64 + sc);
  const bf16_t* vsrc = vh + ((size_t)sr * 4096 + sc);

  bf16x8 qf[4];
#pragma unroll
  for (int ds = 0; ds < 4; ++ds)
    qf[ds] = *(const bf16x8*)(qh + (size_t)qidx * 64 + 16 * ds + 8 * lh);
  bf16x8 ones;
#pragma unroll
  for (int j = 0; j < 8; ++j) ones[j] = (bf16_t)1.0f;

  gld_lds16(ksrc, Ks + tid * 8);
  gld_lds16(vsrc, Vs + tid * 8);
  __syncthreads();

  f32x16 o0 = {}, o1 = {}, osum = {};

  int cur = 0;
  for (int t = 0; t < nst; ++t) {
    if (t + 1 < nst) {  // prefetch next tile into other buffer
      gld_lds16(ksrc + 4096, Ks + (cur ^ 1) * 4096 + tid * 8);
      gld_lds16(vsrc + 64, Vs + (cur ^ 1) * 4096 + tid * 8);
    }
    ksrc += 4096; vsrc += 64;
    const int kvb = t * 64;
    if (kvb <= q0 + 31) {  // causal: this wave still needs this tile
      const bool diag = (kvb + 63 > q0);
      const bf16_t* KsW = Ks + cur * 4096;
      const bf16_t* VsW = Vs + cur * 4096;
      f32x16 st = {};
      __builtin_amdgcn_s_setprio(1);
#pragma unroll
      for (int ds = 0; ds < 4; ++ds) {
        bf16x8 kf = *(const bf16x8*)(KsW + (wc * 4 + ds) * 512 + l * 8);
        st = MFMA32(kf, qf[ds], st);
      }
      __builtin_amdgcn_s_setprio(0);
      float pv[16];
#pragma unroll
      for (int r = 0; r < 16; ++r) pv[r] = __builtin_amdgcn_exp2f(st[r]);
      if (diag) {
        const int kb0 = kvb + wc * 32 + 4 * lh;
#pragma unroll
        for (int r = 0; r < 16; ++r)
          if (kb0 + (r & 3) + 8 * (r >> 2) > qidx) pv[r] = 0.f;
      }
      u32 pq[8];
#pragma unroll
      for (int g = 0; g < 8; ++g) pq[g] = cvt_pk_bf16(pv[2 * g], pv[2 * g + 1]);
#pragma unroll
      for (int ks2 = 0; ks2 < 2; ++ks2) {
        asm("v_permlane32_swap_b32 %0, %1" : "+v"(pq[4 * ks2 + 0]), "+v"(pq[4 * ks2 + 2]));
        asm("v_permlane32_swap_b32 %0, %1" : "+v"(pq[4 * ks2 + 1]), "+v"(pq[4 * ks2 + 3]));
      }
      __builtin_amdgcn_s_setprio(1);
#pragma unroll
      for (int ks = 0; ks < 2; ++ks) {
        bf16x8 pa = *(const bf16x8*)&pq[ks * 4];
        bf16x8 v0 = *(const bf16x8*)(VsW + (2 * wc + ks) * 512 + l * 8);
        bf16x8 v1 = *(const bf16x8*)(VsW + (4 + 2 * wc + ks) * 512 + l * 8);
        o0 = MFMA32(pa, v0, o0);
        o1 = MFMA32(pa, v1, o1);
        osum = MFMA32(pa, ones, osum);   // row-sums of P on the MFMA pipe
      }
      __builtin_amdgcn_s_setprio(0);
    }
    __syncthreads();
    cur ^= 1;
  }

  if (wc == 1) {
#pragma unroll
    for (int r = 0; r < 16; ++r) {
      osh[wq * 2048 + r * 64 + l] = o0[r];
      osh[wq * 2048 + (16 + r) * 64 + l] = o1[r];
    }
    if (lq == 0) {
#pragma unroll
      for (int r = 0; r < 16; ++r)
        lsh[wq * 32 + (r & 3) + 8 * (r >> 2) + 4 * lh] = osum[r];
    }
  }
  __syncthreads();
  if (wc == 0) {
#pragma unroll
    for (int r = 0; r < 16; ++r) {
      o0[r] += osh[wq * 2048 + r * 64 + l];
      o1[r] += osh[wq * 2048 + (16 + r) * 64 + l];
    }
    float linv[16];
#pragma unroll
    for (int r = 0; r < 16; ++r) {
      const int rl = (r & 3) + 8 * (r >> 2) + 4 * lh;
      linv[r] = 1.0f / (osum[r] + lsh[wq * 32 + rl]);
    }
    const int b = hb / 12, h = hb - b * 12;
#pragma unroll
    for (int r = 0; r < 16; ++r) {
      const int row = q0 + (r & 3) + 8 * (r >> 2) + 4 * lh;
      bf16_t* yr = y + ((size_t)b * 4096 + row) * 768 + h * 64 + lq;
      yr[0]  = (bf16_t)(o0[r] * linv[r]);
      yr[32] = (bf16_t)(o1[r] * linv[r]);
    }
  }
}

// ---------------- output GEMM: 64x128 tile (grid 768 = 3/CU; was 384 = 1.5/CU) ----------------
// A-tile 64x64 (8KB), B-tile 128x64 (16KB). 4 waves: wave wc owns rows 0..63 x cols
// wc*32..wc*32+31 (acc[4][2]). Same verified chunk-XOR swizzle; XCD bm-affinity.
__global__ __launch_bounds__(256, 5) void gemm_out(
    const bf16_t* __restrict__ A, const bf16_t* __restrict__ B,
    const float* __restrict__ bias, float* __restrict__ out) {
  __shared__ __align__(16) bf16_t As[64 * 64];
  __shared__ __align__(16) bf16_t Bs[128 * 64];
  const int K = 768;
  const int p = blockIdx.x;
  const int xcd = p & 7, u = p >> 3;           // u in 0..95
  const int bm = xcd * 16 + u / 6;             // 16 bm rows per XCD (128 total)
  const int bn = u - (u / 6) * 6;
  const int tid = threadIdx.x;
  const int w = tid >> 6, l = tid & 63, lg = l >> 4, ln = l & 15;
  const int wc = w;                            // wave column 0..3 (32 cols each)
  const int lr8 = l >> 3, lc8 = l & 7;
  const int ln7 = ln & 7;
  f32x4 acc[4][2] = {};
  for (int kb = 0; kb < K / 64; ++kb) {
    const int k0 = kb * 64;
#pragma unroll
    for (int i = 0; i < 2; ++i) {              // A: 64 rows, 2 chunk-passes
      const int row = w * 16 + i * 8 + lr8;
      const int so = k0 + ((lc8 ^ (row & 7)) << 3);
      gld_lds16(A + (size_t)(bm * 64 + row) * K + so, As + (w * 16 + i * 8) * 64 + l * 8);
    }
#pragma unroll
    for (int i = 0; i < 4; ++i) {              // B: 128 rows, 4 chunk-passes
      const int row = w * 32 + i * 8 + lr8;
      const int so = k0 + ((lc8 ^ (row & 7)) << 3);
      gld_lds16(B + (size_t)(bn * 128 + row) * K + so, Bs + (w * 32 + i * 8) * 64 + l * 8);
    }
    __syncthreads();
#pragma unroll
    for (int kk = 0; kk < 2; ++kk) {
      const int jc = ((kk * 4 + lg) ^ ln7) << 3;
      bf16x8 af[4], bfr[2];
#pragma unroll
      for (int m = 0; m < 4; ++m)
        af[m] = *(const bf16x8*)(As + (m * 16 + ln) * 64 + jc);
#pragma unroll
      for (int n = 0; n < 2; ++n)
        bfr[n] = *(const bf16x8*)(Bs + (wc * 32 + n * 16 + ln) * 64 + jc);
#pragma unroll
      for (int m = 0; m < 4; ++m)
#pragma unroll
        for (int n = 0; n < 2; ++n) acc[m][n] = MFMA16(af[m], bfr[n], acc[m][n]);
    }
    __syncthreads();
  }
#pragma unroll
  for (int m = 0; m < 4; ++m) {
#pragma unroll
    for (int n = 0; n < 2; ++n) {
#pragma unroll
      for (int j = 0; j < 4; ++j) {
        const int gm = bm * 64 + m * 16 + lg * 4 + j;
        const int gn = bn * 128 + wc * 32 + n * 16 + ln;
        out[(size_t)gm * 768 + gn] = acc[m][n][j] + bias[gn];
      }
    }
  }
}

// ---------------- launch ----------------
extern "C" void kernel_launch(void* const* d_in, const int* in_sizes, int n_in,
                              void* d_out, int out_size, void* d_ws, size_t ws_size,
                              hipStream_t stream) {
  const float* x  = (const float*)d_in[0];
  const float* Wq = (const float*)d_in[1];
  const float* bq = (const float*)d_in[2];
  const float* Wk = (const float*)d_in[3];
  const float* bk = (const float*)d_in[4];
  const float* Wv = (const float*)d_in[5];
  const float* bv = (const float*)d_in[6];
  const float* Wo = (const float*)d_in[7];
  const float* bo = (const float*)d_in[8];
  float* out = (float*)d_out;

  const int M = 8192, C = 768, QKV = 2304;
  bf16_t* xb   = (bf16_t*)d_ws;                    // [8192][768]
  bf16_t* wqkv = xb + (size_t)M * C;               // [2304][768]
  bf16_t* wob  = wqkv + (size_t)QKV * C;           // [768][768]
  float*  qkvb = (float*)(wob + (size_t)C * C);    // [2304]
  bf16_t* qbuf = (bf16_t*)(qkvb + QKV);            // [B,H,T,D] (q pre-scaled)
  bf16_t* kbuf = qbuf + (size_t)M * C;             // [B,H,T,D]
  bf16_t* vtb  = kbuf + (size_t)M * C;             // [B,H,D,T]
  bf16_t* yb   = xb;                               // reuse xb (dead after gemm_qkv)

  cast_f32_bf16<<<6144, 256, 0, stream>>>(x, xb, M * C);
  prep_w<<<2304, 256, 0, stream>>>(Wq, Wk, Wv, Wo, bq, bk, bv, wqkv, wob, qkvb);

  gemm_qkv<<<1152, 256, 0, stream>>>(xb, wqkv, qkvb, qbuf, kbuf, vtb);
  attn_fwd<<<768, 512, 0, stream>>>(qbuf, kbuf, vtb, yb);
  gemm_out<<<768, 256, 0, stream>>>(yb, wob, bo, out);
}

// Round 17
// 150.347 us; speedup vs baseline: 3.7478x; 3.7478x over previous
//
#include <hip/hip_runtime.h>

typedef __bf16 bf16_t;
typedef __bf16 bf16x4 __attribute__((ext_vector_type(4)));
typedef __bf16 bf16x8 __attribute__((ext_vector_type(8)));
typedef float  f32x4  __attribute__((ext_vector_type(4)));
typedef float  f32x16 __attribute__((ext_vector_type(16)));
typedef unsigned int u32;

#define MFMA16(a, b, c) __builtin_amdgcn_mfma_f32_16x16x32_bf16((a), (b), (c), 0, 0, 0)
#define MFMA32(a, b, c) __builtin_amdgcn_mfma_f32_32x32x16_bf16((a), (b), (c), 0, 0, 0)

__device__ __forceinline__ void gld_lds16(const bf16_t* g, bf16_t* l) {
  __builtin_amdgcn_global_load_lds((__attribute__((address_space(1))) void*)g,
                                   (__attribute__((address_space(3))) void*)l, 16, 0, 0);
}
__device__ __forceinline__ u32 cvt_pk_bf16(float lo, float hi) {
  u32 r;
  asm("v_cvt_pk_bf16_f32 %0, %1, %2" : "=v"(r) : "v"(lo), "v"(hi));
  return r;
}

// ---------------- prep: x cast (big) ----------------
__global__ void cast_f32_bf16(const float* __restrict__ s, bf16_t* __restrict__ d, int n) {
  int i = (blockIdx.x * blockDim.x + threadIdx.x) * 4;
  if (i >= n) return;
  float4 v = *(const float4*)(s + i);
  bf16x4 o;
  o[0] = (bf16_t)v.x; o[1] = (bf16_t)v.y; o[2] = (bf16_t)v.z; o[3] = (bf16_t)v.w;
  *(bf16x4*)(d + i) = o;
}

// ---------------- prep: all weight casts + bias concat in one launch ----------------
__global__ void prep_w(const float* __restrict__ Wq, const float* __restrict__ Wk,
                       const float* __restrict__ Wv, const float* __restrict__ Wo,
                       const float* __restrict__ bq, const float* __restrict__ bk,
                       const float* __restrict__ bv,
                       bf16_t* __restrict__ wqkv, bf16_t* __restrict__ wob,
                       float* __restrict__ qkvb) {
  const int NW = 768 * 768;
  const int t = blockIdx.x * 256 + threadIdx.x;
  const int i = t * 4;
  if (i < 3 * NW) {
    const float* s; int off;
    if (i < NW)          { s = Wq; off = i; }
    else if (i < 2 * NW) { s = Wk; off = i - NW; }
    else                 { s = Wv; off = i - 2 * NW; }
    float4 v = *(const float4*)(s + off);
    bf16x4 o;
    o[0] = (bf16_t)v.x; o[1] = (bf16_t)v.y; o[2] = (bf16_t)v.z; o[3] = (bf16_t)v.w;
    *(bf16x4*)(wqkv + i) = o;
  } else if (i < 4 * NW) {
    const int off = i - 3 * NW;
    float4 v = *(const float4*)(Wo + off);
    bf16x4 o;
    o[0] = (bf16_t)v.x; o[1] = (bf16_t)v.y; o[2] = (bf16_t)v.z; o[3] = (bf16_t)v.w;
    *(bf16x4*)(wob + off) = o;
  }
  if (t < 2304) qkvb[t] = t < 768 ? bq[t] : (t < 1536 ? bk[t - 768] : bv[t - 1536]);
}

// ---------------- fused QKV GEMM: region branch hoisted OUTSIDE the K-loop ----------------
// R9-verified body; the block-uniform region==2 branch now selects between two complete
// loop copies (each with a single MFMA operand order) so the allocator carries only one
// path's pressure: VGPR ~136 -> ~95-105 -> 4-5 blocks/CU naturally (no forced bounds —
// R16's (256,5) caused a 48-VGPR scratch-spill disaster).
__global__ __launch_bounds__(256) void gemm_qkv(
    const bf16_t* __restrict__ A, const bf16_t* __restrict__ B,
    const float* __restrict__ bias,
    bf16_t* __restrict__ qb, bf16_t* __restrict__ kb2, bf16_t* __restrict__ vtb) {
  __shared__ __align__(16) bf16_t As[128 * 64];
  __shared__ __align__(16) bf16_t Bs[128 * 64];
  const int K = 768;
  const int p = blockIdx.x;
  const int xcd = p & 7, u = p >> 3;           // u in 0..143
  const int bm = xcd * 8 + u / 18;             // 8 bm rows per XCD
  const int bn = u - (u / 18) * 18;            // bn fastest within a bm
  const int tid = threadIdx.x;
  const int w = tid >> 6, l = tid & 63, lg = l >> 4, ln = l & 15;
  const int wr = w >> 1, wc = w & 1;
  const int lr8 = l >> 3, lc8 = l & 7;
  const int region = (bn * 128) / 768;
  const int ln7 = ln & 7;
  f32x4 acc[4][4] = {};
  if (region != 2) {  // ---- q/k path: normal operand order ----
    for (int kb = 0; kb < K / 64; ++kb) {
      const int k0 = kb * 64;
#pragma unroll
      for (int i = 0; i < 4; ++i) {
        const int row = w * 32 + i * 8 + lr8;
        const int so = k0 + ((lc8 ^ (row & 7)) << 3);
        gld_lds16(A + (size_t)(bm * 128 + row) * K + so, As + (w * 32 + i * 8) * 64 + l * 8);
        gld_lds16(B + (size_t)(bn * 128 + row) * K + so, Bs + (w * 32 + i * 8) * 64 + l * 8);
      }
      __syncthreads();
#pragma unroll
      for (int kk = 0; kk < 2; ++kk) {
        bf16x8 af[4], bfr[4];
#pragma unroll
        for (int m = 0; m < 4; ++m) {
          const int jc = ((kk * 4 + lg) ^ ln7) << 3;
          af[m]  = *(const bf16x8*)(As + (wr * 64 + m * 16 + ln) * 64 + jc);
          bfr[m] = *(const bf16x8*)(Bs + (wc * 64 + m * 16 + ln) * 64 + jc);
        }
#pragma unroll
        for (int m = 0; m < 4; ++m)
#pragma unroll
          for (int n = 0; n < 4; ++n) acc[m][n] = MFMA16(af[m], bfr[n], acc[m][n]);
      }
      __syncthreads();
    }
    const float scl = (region == 0) ? 0.18033688011112042f : 1.0f;  // 0.125*log2(e)
    bf16_t* dst = region == 0 ? qb : kb2;
#pragma unroll
    for (int m = 0; m < 4; ++m)
#pragma unroll
      for (int n = 0; n < 4; ++n)
#pragma unroll
        for (int j = 0; j < 4; ++j) {
          const int gm = bm * 128 + wr * 64 + m * 16 + lg * 4 + j;   // t
          const int gn = bn * 128 + wc * 64 + n * 16 + ln;           // qkv col
          const float v = (acc[m][n][j] + bias[gn]) * scl;
          const int c = gn - region * 768;
          const int bb = gm >> 12, tt = gm & 4095;
          const int hh = c >> 6, d = c & 63;
          dst[((size_t)(bb * 12 + hh) * 4096 + tt) * 64 + d] = (bf16_t)v;
        }
  } else {  // ---- v path: C^T (swapped operands) for coalesced [B,H,D,T] writes ----
    for (int kb = 0; kb < K / 64; ++kb) {
      const int k0 = kb * 64;
#pragma unroll
      for (int i = 0; i < 4; ++i) {
        const int row = w * 32 + i * 8 + lr8;
        const int so = k0 + ((lc8 ^ (row & 7)) << 3);
        gld_lds16(A + (size_t)(bm * 128 + row) * K + so, As + (w * 32 + i * 8) * 64 + l * 8);
        gld_lds16(B + (size_t)(bn * 128 + row) * K + so, Bs + (w * 32 + i * 8) * 64 + l * 8);
      }
      __syncthreads();
#pragma unroll
      for (int kk = 0; kk < 2; ++kk) {
        bf16x8 af[4], bfr[4];
#pragma unroll
        for (int m = 0; m < 4; ++m) {
          const int jc = ((kk * 4 + lg) ^ ln7) << 3;
          af[m]  = *(const bf16x8*)(As + (wr * 64 + m * 16 + ln) * 64 + jc);
          bfr[m] = *(const bf16x8*)(Bs + (wc * 64 + m * 16 + ln) * 64 + jc);
        }
#pragma unroll
        for (int m = 0; m < 4; ++m)
#pragma unroll
          for (int n = 0; n < 4; ++n) acc[m][n] = MFMA16(bfr[n], af[m], acc[m][n]);
      }
      __syncthreads();
    }
#pragma unroll
    for (int m = 0; m < 4; ++m)
#pragma unroll
      for (int n = 0; n < 4; ++n)
#pragma unroll
        for (int j = 0; j < 4; ++j) {
          const int gn = bn * 128 + wc * 64 + n * 16 + lg * 4 + j;   // qkv col (channel)
          const int gm = bm * 128 + wr * 64 + m * 16 + ln;           // t
          const float v = acc[m][n][j] + bias[gn];
          const int c = gn - 1536;
          const int bb = gm >> 12, tt = gm & 4095;
          const int hh = c >> 6, d = c & 63;
          vtb[((size_t)(bb * 12 + hh) * 64 + d) * 4096 + tt] = (bf16_t)v;
        }
  }
}

// ---------------- flash attention (R15-verified): shared-tile k-split, 32KB LDS ----------------
__global__ __launch_bounds__(512) void attn_fwd(
    const bf16_t* __restrict__ q, const bf16_t* __restrict__ k,
    const bf16_t* __restrict__ vt, bf16_t* __restrict__ y) {
  __shared__ __align__(16) unsigned char SMEM[33280];
  bf16_t* Ks = (bf16_t*)SMEM;            // [dbuf][4096] (8KB per buf)
  bf16_t* Vs = (bf16_t*)(SMEM + 16384);  // [dbuf][4096]
  float*  osh = (float*)SMEM;            // combine: [4][32][64] f32 (32KB)
  float*  lsh = (float*)(SMEM + 32768);  // combine: [4][32] f32 row sums

  const int p = blockIdx.x;
  const int xcd = p & 7, slot = p >> 3;        // 96 slots per XCD
  const int hb = xcd + 8 * (slot % 3);         // 3 heads per XCD (L2-resident K/V)
  const int qt = 31 - slot / 3;                // heavy-first
  const int tid = threadIdx.x;
  const int w = tid >> 6, l = tid & 63, lq = l & 31, lh = l >> 5;
  const int wq = w >> 1, wc = w & 1;
  const size_t hbo = (size_t)hb * (4096 * 64);
  const bf16_t* qh = q + hbo;
  const bf16_t* kh = k + hbo;
  const bf16_t* vh = vt + hbo;

  const int q0 = qt * 128 + wq * 32;           // wave's first q row
  const int qidx = q0 + lq;                    // this lane's q row
  const int nst = 2 * qt + 2;                  // tiles to sweep (each once)

  const int sr = ((tid >> 8) << 5) | (tid & 31);
  const int sc = ((((tid >> 6) & 3) << 1) | ((tid >> 5) & 1)) << 3;
  const bf16_t* ksrc = kh + ((size_t)sr * 64 + sc);
  const bf16_t* vsrc = vh + ((size_t)sr * 4096 + sc);

  bf16x8 qf[4];
#pragma unroll
  for (int ds = 0; ds < 4; ++ds)
    qf[ds] = *(const bf16x8*)(qh + (size_t)qidx * 64 + 16 * ds + 8 * lh);
  bf16x8 ones;
#pragma unroll
  for (int j = 0; j < 8; ++j) ones[j] = (bf16_t)1.0f;

  gld_lds16(ksrc, Ks + tid * 8);
  gld_lds16(vsrc, Vs + tid * 8);
  __syncthreads();

  f32x16 o0 = {}, o1 = {}, osum = {};

  int cur = 0;
  for (int t = 0; t < nst; ++t) {
    if (t + 1 < nst) {  // prefetch next tile into other buffer
      gld_lds16(ksrc + 4096, Ks + (cur ^ 1) * 4096 + tid * 8);
      gld_lds16(vsrc + 64, Vs + (cur ^ 1) * 4096 + tid * 8);
    }
    ksrc += 4096; vsrc += 64;
    const int kvb = t * 64;
    if (kvb <= q0 + 31) {  // causal: this wave still needs this tile
      const bool diag = (kvb + 63 > q0);
      const bf16_t* KsW = Ks + cur * 4096;
      const bf16_t* VsW = Vs + cur * 4096;
      f32x16 st = {};
      __builtin_amdgcn_s_setprio(1);
#pragma unroll
      for (int ds = 0; ds < 4; ++ds) {
        bf16x8 kf = *(const bf16x8*)(KsW + (wc * 4 + ds) * 512 + l * 8);
        st = MFMA32(kf, qf[ds], st);
      }
      __builtin_amdgcn_s_setprio(0);
      float pv[16];
#pragma unroll
      for (int r = 0; r < 16; ++r) pv[r] = __builtin_amdgcn_exp2f(st[r]);
      if (diag) {
        const int kb0 = kvb + wc * 32 + 4 * lh;
#pragma unroll
        for (int r = 0; r < 16; ++r)
          if (kb0 + (r & 3) + 8 * (r >> 2) > qidx) pv[r] = 0.f;
      }
      u32 pq[8];
#pragma unroll
      for (int g = 0; g < 8; ++g) pq[g] = cvt_pk_bf16(pv[2 * g], pv[2 * g + 1]);
#pragma unroll
      for (int ks2 = 0; ks2 < 2; ++ks2) {
        asm("v_permlane32_swap_b32 %0, %1" : "+v"(pq[4 * ks2 + 0]), "+v"(pq[4 * ks2 + 2]));
        asm("v_permlane32_swap_b32 %0, %1" : "+v"(pq[4 * ks2 + 1]), "+v"(pq[4 * ks2 + 3]));
      }
      __builtin_amdgcn_s_setprio(1);
#pragma unroll
      for (int ks = 0; ks < 2; ++ks) {
        bf16x8 pa = *(const bf16x8*)&pq[ks * 4];
        bf16x8 v0 = *(const bf16x8*)(VsW + (2 * wc + ks) * 512 + l * 8);
        bf16x8 v1 = *(const bf16x8*)(VsW + (4 + 2 * wc + ks) * 512 + l * 8);
        o0 = MFMA32(pa, v0, o0);
        o1 = MFMA32(pa, v1, o1);
        osum = MFMA32(pa, ones, osum);   // row-sums of P on the MFMA pipe
      }
      __builtin_amdgcn_s_setprio(0);
    }
    __syncthreads();
    cur ^= 1;
  }

  if (wc == 1) {
#pragma unroll
    for (int r = 0; r < 16; ++r) {
      osh[wq * 2048 + r * 64 + l] = o0[r];
      osh[wq * 2048 + (16 + r) * 64 + l] = o1[r];
    }
    if (lq == 0) {
#pragma unroll
      for (int r = 0; r < 16; ++r)
        lsh[wq * 32 + (r & 3) + 8 * (r >> 2) + 4 * lh] = osum[r];
    }
  }
  __syncthreads();
  if (wc == 0) {
#pragma unroll
    for (int r = 0; r < 16; ++r) {
      o0[r] += osh[wq * 2048 + r * 64 + l];
      o1[r] += osh[wq * 2048 + (16 + r) * 64 + l];
    }
    float linv[16];
#pragma unroll
    for (int r = 0; r < 16; ++r) {
      const int rl = (r & 3) + 8 * (r >> 2) + 4 * lh;
      linv[r] = 1.0f / (osum[r] + lsh[wq * 32 + rl]);
    }
    const int b = hb / 12, h = hb - b * 12;
#pragma unroll
    for (int r = 0; r < 16; ++r) {
      const int row = q0 + (r & 3) + 8 * (r >> 2) + 4 * lh;
      bf16_t* yr = y + ((size_t)b * 4096 + row) * 768 + h * 64 + lq;
      yr[0]  = (bf16_t)(o0[r] * linv[r]);
      yr[32] = (bf16_t)(o1[r] * linv[r]);
    }
  }
}

// ---------------- output GEMM: 64x128 tile, grid 768 = 3/CU (no forced bounds) ----------------
// A-tile 64x64 (8KB), B-tile 128x64 (16KB). Wave w owns rows 0..63 x cols w*32..+31
// (acc[4][2], ~70 VGPR natural). Verified chunk-XOR swizzle; XCD bm-affinity.
__global__ __launch_bounds__(256) void gemm_out(
    const bf16_t* __restrict__ A, const bf16_t* __restrict__ B,
    const float* __restrict__ bias, float* __restrict__ out) {
  __shared__ __align__(16) bf16_t As[64 * 64];
  __shared__ __align__(16) bf16_t Bs[128 * 64];
  const int K = 768;
  const int p = blockIdx.x;
  const int xcd = p & 7, u = p >> 3;           // u in 0..95
  const int bm = xcd * 16 + u / 6;             // 16 bm rows per XCD (128 total)
  const int bn = u - (u / 6) * 6;
  const int tid = threadIdx.x;
  const int w = tid >> 6, l = tid & 63, lg = l >> 4, ln = l & 15;
  const int lr8 = l >> 3, lc8 = l & 7;
  const int ln7 = ln & 7;
  f32x4 acc[4][2] = {};
  for (int kb = 0; kb < K / 64; ++kb) {
    const int k0 = kb * 64;
#pragma unroll
    for (int i = 0; i < 2; ++i) {              // A: 64 rows, 2 chunk-passes
      const int row = w * 16 + i * 8 + lr8;
      const int so = k0 + ((lc8 ^ (row & 7)) << 3);
      gld_lds16(A + (size_t)(bm * 64 + row) * K + so, As + (w * 16 + i * 8) * 64 + l * 8);
    }
#pragma unroll
    for (int i = 0; i < 4; ++i) {              // B: 128 rows, 4 chunk-passes
      const int row = w * 32 + i * 8 + lr8;
      const int so = k0 + ((lc8 ^ (row & 7)) << 3);
      gld_lds16(B + (size_t)(bn * 128 + row) * K + so, Bs + (w * 32 + i * 8) * 64 + l * 8);
    }
    __syncthreads();
#pragma unroll
    for (int kk = 0; kk < 2; ++kk) {
      const int jc = ((kk * 4 + lg) ^ ln7) << 3;
      bf16x8 af[4], bfr[2];
#pragma unroll
      for (int m = 0; m < 4; ++m)
        af[m] = *(const bf16x8*)(As + (m * 16 + ln) * 64 + jc);
#pragma unroll
      for (int n = 0; n < 2; ++n)
        bfr[n] = *(const bf16x8*)(Bs + (w * 32 + n * 16 + ln) * 64 + jc);
#pragma unroll
      for (int m = 0; m < 4; ++m)
#pragma unroll
        for (int n = 0; n < 2; ++n) acc[m][n] = MFMA16(af[m], bfr[n], acc[m][n]);
    }
    __syncthreads();
  }
#pragma unroll
  for (int m = 0; m < 4; ++m) {
#pragma unroll
    for (int n = 0; n < 2; ++n) {
#pragma unroll
      for (int j = 0; j < 4; ++j) {
        const int gm = bm * 64 + m * 16 + lg * 4 + j;
        const int gn = bn * 128 + w * 32 + n * 16 + ln;
        out[(size_t)gm * 768 + gn] = acc[m][n][j] + bias[gn];
      }
    }
  }
}

// ---------------- launch ----------------
extern "C" void kernel_launch(void* const* d_in, const int* in_sizes, int n_in,
                              void* d_out, int out_size, void* d_ws, size_t ws_size,
                              hipStream_t stream) {
  const float* x  = (const float*)d_in[0];
  const float* Wq = (const float*)d_in[1];
  const float* bq = (const float*)d_in[2];
  const float* Wk = (const float*)d_in[3];
  const float* bk = (const float*)d_in[4];
  const float* Wv = (const float*)d_in[5];
  const float* bv = (const float*)d_in[6];
  const float* Wo = (const float*)d_in[7];
  const float* bo = (const float*)d_in[8];
  float* out = (float*)d_out;

  const int M = 8192, C = 768, QKV = 2304;
  bf16_t* xb   = (bf16_t*)d_ws;                    // [8192][768]
  bf16_t* wqkv = xb + (size_t)M * C;               // [2304][768]
  bf16_t* wob  = wqkv + (size_t)QKV * C;           // [768][768]
  float*  qkvb = (float*)(wob + (size_t)C * C);    // [2304]
  bf16_t* qbuf = (bf16_t*)(qkvb + QKV);            // [B,H,T,D] (q pre-scaled)
  bf16_t* kbuf = qbuf + (size_t)M * C;             // [B,H,T,D]
  bf16_t* vtb  = kbuf + (size_t)M * C;             // [B,H,D,T]
  bf16_t* yb   = xb;                               // reuse xb (dead after gemm_qkv)

  cast_f32_bf16<<<6144, 256, 0, stream>>>(x, xb, M * C);
  prep_w<<<2304, 256, 0, stream>>>(Wq, Wk, Wv, Wo, bq, bk, bv, wqkv, wob, qkvb);

  gemm_qkv<<<1152, 256, 0, stream>>>(xb, wqkv, qkvb, qbuf, kbuf, vtb);
  attn_fwd<<<768, 512, 0, stream>>>(qbuf, kbuf, vtb, yb);
  gemm_out<<<768, 256, 0, stream>>>(yb, wob, bo, out);
}